// Round 15
// baseline (140.711 us; speedup 1.0000x reference)
//
#include <hip/hip_runtime.h>

// DSSIM = 1 - mean(SSIM), 11x11 gaussian (sigma=1.5), zero-pad, fp32 in/out.
// MFMA separable conv, transpose-free (exactness verified R14):
//   h-blur: C[m][n] = A[m][k] x Wh[k][n]; Wh[k][n]=g[k-n-3].
//   v-blur: D[m][n] = Wv[m][k] x B[k][n], K permuted by sigma so B == own C
//     fragment; Wv[bn][8jg+j] = g[sigma-bn] (band masks garbage rows).
// R15: depth-2 software pipeline with two register chains (A/B):
//   step i: LOAD(i+2 -> S(i%2)) ; HCOMP(tile i+1) ; VBLUR(frags of tile i)
// fp16-domain u/w adds; NO launch_bounds (every cap tried induced spill).

typedef _Float16 half8 __attribute__((ext_vector_type(8)));
typedef __fp16 pk16 __attribute__((ext_vector_type(2)));   // pkrtz native type
typedef float f32x4 __attribute__((ext_vector_type(4)));
typedef float f32x8 __attribute__((ext_vector_type(8)));

#define IMG_W   512
#define IMG_H   512
#define NPLANES 48
#define BR      16                  // output rows per block
#define GRX     (IMG_H / BR)        // 32
#define NBLK    (GRX * NPLANES)     // 1536

__global__
void dssim_main(const float* __restrict__ xin, const float* __restrict__ yin,
                float* __restrict__ partial) {
    __shared__ float wpart[4];

    const int t    = threadIdx.x;
    const int lane = t & 63;
    const int wid  = t >> 6;
    const int bn   = lane & 15;          // fragment row/col owner
    const int jg   = lane >> 4;          // k-chunk
    const int r0   = blockIdx.x * BR;
    const bool edge = (blockIdx.x == 0) || (blockIdx.x == GRX - 1);
    const size_t pbase = (size_t)blockIdx.y * (IMG_W * IMG_H);
    const float* __restrict__ xp = xin + pbase;
    const float* __restrict__ yp = yin + pbase;

    // gaussian normalization
    float ginv;
    {
        float s = 0.f;
#pragma unroll
        for (int i = 0; i < 11; ++i) {
            float d = (float)(i - 5);
            s += expf(-(d * d) * (1.0f / 4.5f));
        }
        ginv = 1.0f / s;
    }

    // weight fragments (verified R14):
    // whF: lane holds Wh[8jg+j][bn] = g[k-bn-3]
    // wvF: lane holds Wv[bn][8jg+j] = g[sigma(jg,j)-bn],
    //      sigma = 4jg+j (j<4) | 16+4jg+(j-4) (j>=4)
    half8 whF, wvF;
#pragma unroll
    for (int j = 0; j < 8; ++j) {
        const int k = 8 * jg + j;
        const int dh = k - bn - 3;
        const int sigma = (j < 4) ? (4 * jg + j) : (12 + 4 * jg + j);
        const int dv = sigma - bn;
        float wh = 0.f, wv = 0.f;
        if (dh >= 0 && dh < 11) {
            const float d = (float)(dh - 5);
            wh = ginv * expf(-(d * d) * (1.0f / 4.5f));
        }
        if (dv >= 0 && dv < 11) {
            const float d = (float)(dv - 5);
            wv = ginv * expf(-(d * d) * (1.0f / 4.5f));
        }
        whF[j] = (_Float16)wh;
        wvF[j] = (_Float16)wv;
    }

    // row addressing: rt0 raw rows r0-5+bn, rt1 raw rows r0+11+bn
    const int gr0 = r0 - 5 + bn;
    const bool rowok0 = (gr0 >= 0) && (gr0 < IMG_H);
    const int gr1 = r0 + 11 + bn;
    const bool rowok1 = (bn < 10) && (gr1 < IMG_H);
    const size_t row0 = (size_t)(rowok0 ? gr0 : 0) * IMG_W;
    const size_t row1 = (size_t)(rowok1 ? gr1 : 0) * IMG_W;

    // base pointers: col-tile m covers cols (wid+4m)*16 + 8jg-8 .. +8jg-1
    const int cb = (wid << 4) + (jg << 3) - 8;
    const float* bx0 = xp + row0 + cb;
    const float* by0 = yp + row0 + cb;
    const float* bx1 = xp + row1 + cb;
    const float* by1 = yp + row1 + cb;

    const f32x8 z8 = {0.f, 0.f, 0.f, 0.f, 0.f, 0.f, 0.f, 0.f};
    const f32x4 zf = {0.f, 0.f, 0.f, 0.f};
    const float C1 = 0.0001f, C2 = 0.0009f;
    float lsum = 0.f;

    // two full chains: staging sets A/B, fragment sets A/B (all named/static)
    f32x8 xsA0, ysA0, xsA1, ysA1, xsB0, ysB0, xsB1, ysB1;
    half8 bUA, bWA, bPA, bQA, bUB, bWB, bPB, bQB;

    // load col-tile m into staging set S (compile-time m)
#define LOADP(m, S)                                                         \
    {                                                                       \
        int fix = 0;                                                        \
        if ((m) == 0) fix = (wid == 0 && jg == 0) ? 8 : 0;                  \
        if ((m) == 7) fix = (wid == 3 && jg == 3) ? -8 : 0;                 \
        const int off = 64 * (m);                                           \
        xs##S##0 = *(const f32x8*)(bx0 + off + fix);                        \
        ys##S##0 = *(const f32x8*)(by0 + off + fix);                        \
        xs##S##1 = *(const f32x8*)(bx1 + off + fix);                        \
        ys##S##1 = *(const f32x8*)(by1 + off + fix);                        \
        if ((m) == 0) {                                                     \
            if (wid == 0 && jg == 0) { xs##S##0 = z8; ys##S##0 = z8;        \
                                       xs##S##1 = z8; ys##S##1 = z8; }      \
        }                                                                   \
        if ((m) == 7) {                                                     \
            if (wid == 3 && jg == 3) { xs##S##0 = z8; ys##S##0 = z8;        \
                                       xs##S##1 = z8; ys##S##1 = z8; }      \
        }                                                                   \
        if (edge) {                                                         \
            if (!rowok0) { xs##S##0 = z8; ys##S##0 = z8; }                  \
            if (!rowok1) { xs##S##1 = z8; ys##S##1 = z8; }                  \
        }                                                                   \
    }

    // h-blur staging set S -> v B-fragment set F (fp16-domain u/w)
#define HCOMPM(S, F)                                                        \
    {                                                                       \
        half8 hx0, hy0, hx1, hy1;                                           \
        _Pragma("unroll")                                                   \
        for (int d = 0; d < 4; ++d) {                                       \
            const pk16 a0 = __builtin_amdgcn_cvt_pkrtz(xs##S##0[2*d], xs##S##0[2*d+1]); \
            const pk16 b0 = __builtin_amdgcn_cvt_pkrtz(ys##S##0[2*d], ys##S##0[2*d+1]); \
            const pk16 a1 = __builtin_amdgcn_cvt_pkrtz(xs##S##1[2*d], xs##S##1[2*d+1]); \
            const pk16 b1 = __builtin_amdgcn_cvt_pkrtz(ys##S##1[2*d], ys##S##1[2*d+1]); \
            hx0[2*d] = (_Float16)a0[0]; hx0[2*d+1] = (_Float16)a0[1];       \
            hy0[2*d] = (_Float16)b0[0]; hy0[2*d+1] = (_Float16)b0[1];       \
            hx1[2*d] = (_Float16)a1[0]; hx1[2*d+1] = (_Float16)a1[1];       \
            hy1[2*d] = (_Float16)b1[0]; hy1[2*d+1] = (_Float16)b1[1];       \
        }                                                                   \
        const half8 aU0 = hx0 + hy0;                                        \
        const half8 aW0 = hx0 - hy0;                                        \
        const half8 aU1 = hx1 + hy1;                                        \
        const half8 aW1 = hx1 - hy1;                                        \
        const half8 aP0 = aU0 * aU0;                                        \
        const half8 aQ0 = aW0 * aW0;                                        \
        const half8 aP1 = aU1 * aU1;                                        \
        const half8 aQ1 = aW1 * aW1;                                        \
        const f32x4 cU0 = __builtin_amdgcn_mfma_f32_16x16x32_f16(aU0, whF, zf, 0, 0, 0); \
        const f32x4 cW0 = __builtin_amdgcn_mfma_f32_16x16x32_f16(aW0, whF, zf, 0, 0, 0); \
        const f32x4 cP0 = __builtin_amdgcn_mfma_f32_16x16x32_f16(aP0, whF, zf, 0, 0, 0); \
        const f32x4 cQ0 = __builtin_amdgcn_mfma_f32_16x16x32_f16(aQ0, whF, zf, 0, 0, 0); \
        const f32x4 cU1 = __builtin_amdgcn_mfma_f32_16x16x32_f16(aU1, whF, zf, 0, 0, 0); \
        const f32x4 cW1 = __builtin_amdgcn_mfma_f32_16x16x32_f16(aW1, whF, zf, 0, 0, 0); \
        const f32x4 cP1 = __builtin_amdgcn_mfma_f32_16x16x32_f16(aP1, whF, zf, 0, 0, 0); \
        const f32x4 cQ1 = __builtin_amdgcn_mfma_f32_16x16x32_f16(aQ1, whF, zf, 0, 0, 0); \
        _Pragma("unroll")                                                   \
        for (int q = 0; q < 2; ++q) {                                       \
            const pk16 u0 = __builtin_amdgcn_cvt_pkrtz(cU0[2*q], cU0[2*q+1]); \
            const pk16 w0 = __builtin_amdgcn_cvt_pkrtz(cW0[2*q], cW0[2*q+1]); \
            const pk16 p0 = __builtin_amdgcn_cvt_pkrtz(cP0[2*q], cP0[2*q+1]); \
            const pk16 q0 = __builtin_amdgcn_cvt_pkrtz(cQ0[2*q], cQ0[2*q+1]); \
            const pk16 u1 = __builtin_amdgcn_cvt_pkrtz(cU1[2*q], cU1[2*q+1]); \
            const pk16 w1 = __builtin_amdgcn_cvt_pkrtz(cW1[2*q], cW1[2*q+1]); \
            const pk16 p1 = __builtin_amdgcn_cvt_pkrtz(cP1[2*q], cP1[2*q+1]); \
            const pk16 q1 = __builtin_amdgcn_cvt_pkrtz(cQ1[2*q], cQ1[2*q+1]); \
            bU##F[2*q]   = (_Float16)u0[0]; bU##F[2*q+1] = (_Float16)u0[1]; \
            bW##F[2*q]   = (_Float16)w0[0]; bW##F[2*q+1] = (_Float16)w0[1]; \
            bP##F[2*q]   = (_Float16)p0[0]; bP##F[2*q+1] = (_Float16)p0[1]; \
            bQ##F[2*q]   = (_Float16)q0[0]; bQ##F[2*q+1] = (_Float16)q0[1]; \
            bU##F[2*q+4] = (_Float16)u1[0]; bU##F[2*q+5] = (_Float16)u1[1]; \
            bW##F[2*q+4] = (_Float16)w1[0]; bW##F[2*q+5] = (_Float16)w1[1]; \
            bP##F[2*q+4] = (_Float16)p1[0]; bP##F[2*q+5] = (_Float16)p1[1]; \
            bQ##F[2*q+4] = (_Float16)q1[0]; bQ##F[2*q+5] = (_Float16)q1[1]; \
        }                                                                   \
    }

    // v-blur from fragment set F + ssim epilogue
#define VBLURM(F)                                                           \
    {                                                                       \
        const f32x4 accU = __builtin_amdgcn_mfma_f32_16x16x32_f16(wvF, bU##F, zf, 0, 0, 0); \
        const f32x4 accW = __builtin_amdgcn_mfma_f32_16x16x32_f16(wvF, bW##F, zf, 0, 0, 0); \
        const f32x4 accP = __builtin_amdgcn_mfma_f32_16x16x32_f16(wvF, bP##F, zf, 0, 0, 0); \
        const f32x4 accQ = __builtin_amdgcn_mfma_f32_16x16x32_f16(wvF, bQ##F, zf, 0, 0, 0); \
        _Pragma("unroll")                                                   \
        for (int q = 0; q < 4; ++q) {                                       \
            const float U = accU[q], W = accW[q];                           \
            const float P = accP[q], Q = accQ[q];                           \
            const float U2 = U * U, W2 = W * W;                             \
            const float A = 0.5f * (U2 + W2);                               \
            const float B = 0.5f * (U2 - W2);                               \
            const float den2 = fmaf(0.5f, P + Q, -A) + C2;                  \
            const float num2 = fmaf(0.5f, P - Q, -B) + C2;                  \
            lsum += (B + C1) * num2 * __builtin_amdgcn_rcpf((A + C1) * den2); \
        }                                                                   \
    }

    // depth-2 pipeline over 8 col-tiles, two chains (A: even, B: odd)
    LOADP(0, A); LOADP(1, B);
    HCOMPM(A, A);
    /*0*/ LOADP(2, A); HCOMPM(B, B); VBLURM(A);
    /*1*/ LOADP(3, B); HCOMPM(A, A); VBLURM(B);
    /*2*/ LOADP(4, A); HCOMPM(B, B); VBLURM(A);
    /*3*/ LOADP(5, B); HCOMPM(A, A); VBLURM(B);
    /*4*/ LOADP(6, A); HCOMPM(B, B); VBLURM(A);
    /*5*/ LOADP(7, B); HCOMPM(A, A); VBLURM(B);
    /*6*/              HCOMPM(B, B); VBLURM(A);
    /*7*/                            VBLURM(B);

    // ---- block reduction ----
#pragma unroll
    for (int off = 32; off >= 1; off >>= 1)
        lsum += __shfl_down(lsum, off, 64);
    if (lane == 0) wpart[wid] = lsum;
    __syncthreads();
    if (t == 0) {
        partial[(size_t)blockIdx.y * GRX + blockIdx.x] =
            wpart[0] + wpart[1] + wpart[2] + wpart[3];
    }
}

__global__ __launch_bounds__(256)
void dssim_final(const float* __restrict__ partial, float* __restrict__ out) {
    __shared__ double wsum[4];
    double s = 0.0;
    for (int i = threadIdx.x; i < NBLK; i += 256) s += (double)partial[i];
#pragma unroll
    for (int off = 32; off >= 1; off >>= 1)
        s += __shfl_down(s, off, 64);
    if ((threadIdx.x & 63) == 0) wsum[threadIdx.x >> 6] = s;
    __syncthreads();
    if (threadIdx.x == 0) {
        const double tot = wsum[0] + wsum[1] + wsum[2] + wsum[3];
        out[0] = (float)(1.0 - tot / 12582912.0);
    }
}

extern "C" void kernel_launch(void* const* d_in, const int* in_sizes, int n_in,
                              void* d_out, int out_size, void* d_ws, size_t ws_size,
                              hipStream_t stream) {
    const float* x = (const float*)d_in[0];
    const float* y = (const float*)d_in[1];
    float* out = (float*)d_out;
    float* partial = (float*)d_ws;   // NBLK*4 = 6 KiB

    dim3 grid(GRX, NPLANES);         // 32 x 48 = 1536 blocks
    dim3 block(256);
    dssim_main<<<grid, block, 0, stream>>>(x, y, partial);
    dssim_final<<<1, block, 0, stream>>>(partial, out);
}

// Round 16
// 48.828 us; speedup vs baseline: 2.8817x; 2.8817x over previous
//
#include <hip/hip_runtime.h>

// DSSIM = 1 - mean(SSIM), 11x11 gaussian (sigma=1.5), zero-pad, fp32 in/out.
// MFMA separable conv (layout verified exact since R7):
//   h-blur: C[m][n] = A[m][k] x Wh[k][n]; Wh[k][n]=g[k-n-3]
//   v-blur: C[col][n] = AT[col][k] x Wv[k][n]; AT via LDS transpose
// R16 = R12 (best: 48.3 us, spill-free at (256,3)) + codegen fixes:
//   - union-bitcast fragment packing: pkrtz result placed as a dword, not
//     16 element-wise _Float16 inserts (kills v_bfi/v_or storm)
//   - f32x8 vector adds for u/w (v_pk_add_f32)

typedef _Float16 half8 __attribute__((ext_vector_type(8)));
typedef _Float16 half4v __attribute__((ext_vector_type(4)));
typedef __fp16 pk16 __attribute__((ext_vector_type(2)));   // pkrtz native type
typedef float f32x4 __attribute__((ext_vector_type(4)));
typedef float f32x8 __attribute__((ext_vector_type(8)));

#define IMG_W   512
#define IMG_H   512
#define NPLANES 48
#define BR      16                  // output rows per block
#define TP      40                  // ldsT k-pitch (halves); 80 B
#define GRX     (IMG_H / BR)        // 32
#define NBLK    (GRX * NPLANES)     // 1536

__device__ __forceinline__ unsigned pkrtz_u(float a, float b) {
    union { pk16 p; unsigned u; } c;
    c.p = __builtin_amdgcn_cvt_pkrtz(a, b);
    return c.u;
}

__global__ __launch_bounds__(256, 3)
void dssim_main(const float* __restrict__ xin, const float* __restrict__ yin,
                float* __restrict__ partial) {
    __shared__ _Float16 ldsT[4][4][16][TP];   // [wave][ch][col][k]  20.5 KB
    __shared__ float wpart[4];

    const int t    = threadIdx.x;
    const int lane = t & 63;
    const int wid  = t >> 6;
    const int bn   = lane & 15;          // fragment row/col owner
    const int jg   = lane >> 4;          // k-chunk
    const int swz  = (bn & 8) << 1;      // XOR on k-index (halves)
    const int r0   = blockIdx.x * BR;
    const size_t pbase = (size_t)blockIdx.y * (IMG_W * IMG_H);
    const float* __restrict__ xp = xin + pbase;
    const float* __restrict__ yp = yin + pbase;

    // gaussian normalization
    float ginv;
    {
        float s = 0.f;
#pragma unroll
        for (int i = 0; i < 11; ++i) {
            float d = (float)(i - 5);
            s += expf(-(d * d) * (1.0f / 4.5f));
        }
        ginv = 1.0f / s;
    }

    // banded weight fragments (B-operand: lane holds B[8*jg+j][bn])
    half8 whF, wvF;
#pragma unroll
    for (int j = 0; j < 8; ++j) {
        const int k = 8 * jg + j;
        const int dh = k - bn - 3;       // h band: g[k-n-3]
        const int dv = k - bn;           // v band: g[k-n]
        float wh = 0.f, wv = 0.f;
        if (dh >= 0 && dh < 11) {
            const float d = (float)(dh - 5);
            wh = ginv * expf(-(d * d) * (1.0f / 4.5f));
        }
        if (dv >= 0 && dv < 11) {
            const float d = (float)(dv - 5);
            wv = ginv * expf(-(d * d) * (1.0f / 4.5f));
        }
        whF[j] = (_Float16)wh;
        wvF[j] = (_Float16)wv;
    }

    // row addressing (iteration-invariant): rt0 rows bn, rt1 rows 16+bn
    const int gr0 = r0 - 5 + bn;
    const bool rowok0 = (gr0 >= 0) && (gr0 < IMG_H);
    const int gr1 = r0 + 11 + bn;
    const bool rowok1 = (bn < 10) && (gr1 < IMG_H);
    const size_t row0 = (size_t)(rowok0 ? gr0 : 0) * IMG_W;
    const size_t row1 = (size_t)(rowok1 ? gr1 : 0) * IMG_W;

    const f32x8 z8 = {0.f, 0.f, 0.f, 0.f, 0.f, 0.f, 0.f, 0.f};
    const f32x4 zf = {0.f, 0.f, 0.f, 0.f};
    const float C1 = 0.0001f, C2 = 0.0009f;
    float lsum = 0.f;

    f32x8 xs0, ys0, xs1, ys1;          // staged raw rows (named, static)

    // issue global loads for col-tile ii (k-window cols c0-8 .. c0+23)
#define LOADI(ii)                                                           \
    {                                                                       \
        const int col = (((wid + 4 * (ii)) << 4) + 8 * jg) - 8;             \
        const bool colok = (col >= 0) && (col < IMG_W);                     \
        const size_t co = (size_t)(colok ? col : 0);                        \
        const bool ok0 = colok && rowok0, ok1 = colok && rowok1;            \
        xs0 = ok0 ? *(const f32x8*)(xp + row0 + co) : z8;                   \
        ys0 = ok0 ? *(const f32x8*)(yp + row0 + co) : z8;                   \
        xs1 = ok1 ? *(const f32x8*)(xp + row1 + co) : z8;                   \
        ys1 = ok1 ? *(const f32x8*)(yp + row1 + co) : z8;                   \
    }

    // h-blur both row-tiles of col-tile ii into ldsT (single buffer)
#define HCOMPI(ii)                                                          \
    {                                                                       \
        _Pragma("unroll")                                                   \
        for (int rt = 0; rt < 2; ++rt) {                                    \
            const f32x8 xv = rt ? xs1 : xs0;                                \
            const f32x8 yv = rt ? ys1 : ys0;                                \
            const f32x8 su = xv + yv;                                       \
            const f32x8 sw = xv - yv;                                       \
            union { unsigned u[4]; half8 h; } aU, aW;                       \
            _Pragma("unroll")                                               \
            for (int d = 0; d < 4; ++d) {                                   \
                aU.u[d] = pkrtz_u(su[2 * d], su[2 * d + 1]);                \
                aW.u[d] = pkrtz_u(sw[2 * d], sw[2 * d + 1]);                \
            }                                                               \
            const half8 aU2 = aU.h * aU.h;                                  \
            const half8 aW2 = aW.h * aW.h;                                  \
            const f32x4 cU  = __builtin_amdgcn_mfma_f32_16x16x32_f16(aU.h, whF, zf, 0, 0, 0); \
            const f32x4 cW  = __builtin_amdgcn_mfma_f32_16x16x32_f16(aW.h, whF, zf, 0, 0, 0); \
            const f32x4 cU2 = __builtin_amdgcn_mfma_f32_16x16x32_f16(aU2,  whF, zf, 0, 0, 0); \
            const f32x4 cW2 = __builtin_amdgcn_mfma_f32_16x16x32_f16(aW2,  whF, zf, 0, 0, 0); \
            union { unsigned u[2]; half4v h; } hU, hW, hU2, hW2;            \
            _Pragma("unroll")                                               \
            for (int q = 0; q < 2; ++q) {                                   \
                hU.u[q]  = pkrtz_u(cU[2 * q],  cU[2 * q + 1]);              \
                hW.u[q]  = pkrtz_u(cW[2 * q],  cW[2 * q + 1]);              \
                hU2.u[q] = pkrtz_u(cU2[2 * q], cU2[2 * q + 1]);             \
                hW2.u[q] = pkrtz_u(cW2[2 * q], cW2[2 * q + 1]);             \
            }                                                               \
            const int kk = (16 * rt + 4 * jg) ^ swz;                        \
            *(half4v*)&ldsT[wid][0][bn][kk] = hU.h;                         \
            *(half4v*)&ldsT[wid][1][bn][kk] = hW.h;                         \
            *(half4v*)&ldsT[wid][2][bn][kk] = hU2.h;                        \
            *(half4v*)&ldsT[wid][3][bn][kk] = hW2.h;                        \
        }                                                                   \
    }

    // v-blur col-tile ii from ldsT + ssim epilogue
#define VBLURI(ii)                                                          \
    {                                                                       \
        const int kb = (8 * jg) ^ swz;                                      \
        const half8 aTU  = *(const half8*)&ldsT[wid][0][bn][kb];            \
        const half8 aTW  = *(const half8*)&ldsT[wid][1][bn][kb];            \
        const half8 aTU2 = *(const half8*)&ldsT[wid][2][bn][kb];            \
        const half8 aTW2 = *(const half8*)&ldsT[wid][3][bn][kb];            \
        const f32x4 accU = __builtin_amdgcn_mfma_f32_16x16x32_f16(aTU,  wvF, zf, 0, 0, 0); \
        const f32x4 accW = __builtin_amdgcn_mfma_f32_16x16x32_f16(aTW,  wvF, zf, 0, 0, 0); \
        const f32x4 accP = __builtin_amdgcn_mfma_f32_16x16x32_f16(aTU2, wvF, zf, 0, 0, 0); \
        const f32x4 accQ = __builtin_amdgcn_mfma_f32_16x16x32_f16(aTW2, wvF, zf, 0, 0, 0); \
        _Pragma("unroll")                                                   \
        for (int q = 0; q < 4; ++q) {                                       \
            const float U = accU[q], W = accW[q];                           \
            const float P = accP[q], Q = accQ[q];                           \
            const float U2 = U * U, W2 = W * W;                             \
            const float A = 0.5f * (U2 + W2);                               \
            const float B = 0.5f * (U2 - W2);                               \
            const float den2 = fmaf(0.5f, P + Q, -A) + C2;                  \
            const float num2 = fmaf(0.5f, P - Q, -B) + C2;                  \
            lsum += (B + C1) * num2 * __builtin_amdgcn_rcpf((A + C1) * den2); \
        }                                                                   \
    }

    // software pipeline: load(i+1) || vblur(i), no barriers
    LOADI(0);
    HCOMPI(0);
#pragma unroll
    for (int i = 0; i < 8; ++i) {
        if (i + 1 < 8) LOADI(i + 1);
        VBLURI(i);
        if (i + 1 < 8) HCOMPI(i + 1);
    }

    // ---- block reduction ----
#pragma unroll
    for (int off = 32; off >= 1; off >>= 1)
        lsum += __shfl_down(lsum, off, 64);
    if (lane == 0) wpart[wid] = lsum;
    __syncthreads();
    if (t == 0) {
        partial[(size_t)blockIdx.y * GRX + blockIdx.x] =
            wpart[0] + wpart[1] + wpart[2] + wpart[3];
    }
}

__global__ __launch_bounds__(256)
void dssim_final(const float* __restrict__ partial, float* __restrict__ out) {
    __shared__ double wsum[4];
    double s = 0.0;
    for (int i = threadIdx.x; i < NBLK; i += 256) s += (double)partial[i];
#pragma unroll
    for (int off = 32; off >= 1; off >>= 1)
        s += __shfl_down(s, off, 64);
    if ((threadIdx.x & 63) == 0) wsum[threadIdx.x >> 6] = s;
    __syncthreads();
    if (threadIdx.x == 0) {
        const double tot = wsum[0] + wsum[1] + wsum[2] + wsum[3];
        out[0] = (float)(1.0 - tot / 12582912.0);
    }
}

extern "C" void kernel_launch(void* const* d_in, const int* in_sizes, int n_in,
                              void* d_out, int out_size, void* d_ws, size_t ws_size,
                              hipStream_t stream) {
    const float* x = (const float*)d_in[0];
    const float* y = (const float*)d_in[1];
    float* out = (float*)d_out;
    float* partial = (float*)d_ws;   // NBLK*4 = 6 KiB

    dim3 grid(GRX, NPLANES);         // 32 x 48 = 1536 blocks
    dim3 block(256);
    dssim_main<<<grid, block, 0, stream>>>(x, y, partial);
    dssim_final<<<1, block, 0, stream>>>(partial, out);
}